// Round 1
// baseline (687.969 us; speedup 1.0000x reference)
//
#include <hip/hip_runtime.h>
#include <math.h>

// Problem shape (fixed by the reference): B=16, S=4096, E=2048, WIN=64.
#define EDIM 2048
#define SLEN 4096
#define ROWS_PER_WAVE 8

// Stage 1: GEMV scores = x @ W + b, masked.
// One wave (64 lanes) per row; W fragment cached in registers (32 VGPRs/lane);
// no LDS, no barriers. Each wave streams 8 consecutive rows so block setup
// amortizes over 64 KB of x traffic. Grid: 65536 rows / (4 waves * 8 rows) = 2048 blocks.
__global__ __launch_bounds__(256) void score_kernel(
    const float* __restrict__ x,
    const int*   __restrict__ mask,
    const float* __restrict__ W,
    const float* __restrict__ bias,
    float* __restrict__ s_out)
{
    const int tid  = threadIdx.x;
    const int wave = tid >> 6;
    const int lane = tid & 63;

    // W fragment in registers: lane i holds W4[i + 64k], k=0..7.
    // Same lane->element mapping as the x loads below, so FMA pairs line up.
    const float4* W4 = (const float4*)W;
    float4 wf[8];
#pragma unroll
    for (int k = 0; k < 8; ++k)
        wf[k] = W4[lane + 64 * k];

    const float bval = bias[0];

    const int gwave = blockIdx.x * 4 + wave;
    int row = gwave * ROWS_PER_WAVE;
    const float4* x4 = (const float4*)(x + (size_t)row * EDIM);

    for (int r = 0; r < ROWS_PER_WAVE; ++r, ++row, x4 += EDIM / 4) {
        float acc = 0.0f;
#pragma unroll
        for (int k = 0; k < 8; ++k) {
            float4 xv = x4[lane + 64 * k];   // coalesced: wave covers 1 KiB/instr
            acc = fmaf(xv.x, wf[k].x, acc);
            acc = fmaf(xv.y, wf[k].y, acc);
            acc = fmaf(xv.z, wf[k].z, acc);
            acc = fmaf(xv.w, wf[k].w, acc);
        }
        // Wave-level reduction across all 64 lanes (same order as previous
        // passing kernel -> bit-identical scores).
#pragma unroll
        for (int off = 32; off > 0; off >>= 1)
            acc += __shfl_down(acc, off, 64);

        if (lane == 0)
            s_out[row] = mask[row] ? (acc + bval) : 0.0f;
    }
}

// Stage 2: one block per batch (16 blocks). Scores staged in LDS via float4;
// each thread computes direct 64-element window sums for strided positions,
// tracks local max; block max-reduce. max(mean) == max(sum)/win since win > 0.
__global__ __launch_bounds__(1024) void window_max_kernel(
    const float* __restrict__ s,
    const int*   __restrict__ win_ptr,
    float* __restrict__ out)
{
    __shared__ float sh[SLEN];      // 16 KB
    __shared__ float red[1024];     // 4 KB

    const int b   = blockIdx.x;
    const int tid = threadIdx.x;
    const float* sb = s + (size_t)b * SLEN;

    // 4096 floats = 1024 float4: one vector load per thread.
    ((float4*)sh)[tid] = ((const float4*)sb)[tid];
    __syncthreads();

    const int win  = *win_ptr;
    const int npos = SLEN - win + 1;

    float best = -INFINITY;
    for (int p = tid; p < npos; p += 1024) {
        float sum = 0.0f;
        for (int j = 0; j < win; ++j)      // same j-order as before: exact sums
            sum += sh[p + j];
        best = fmaxf(best, sum);
    }

    red[tid] = best;
    __syncthreads();
    for (int k = 512; k > 0; k >>= 1) {
        if (tid < k) red[tid] = fmaxf(red[tid], red[tid + k]);
        __syncthreads();
    }
    if (tid == 0)
        out[b] = red[0] / (float)win;
}

extern "C" void kernel_launch(void* const* d_in, const int* in_sizes, int n_in,
                              void* d_out, int out_size, void* d_ws, size_t ws_size,
                              hipStream_t stream) {
    const float* x    = (const float*)d_in[0];  // [B,S,E] f32
    const int*   mask = (const int*)  d_in[1];  // [B,S]   bool->int
    const float* W    = (const float*)d_in[2];  // [E]     f32
    const float* bias = (const float*)d_in[3];  // [1]     f32
    const int*   win  = (const int*)  d_in[4];  // scalar  int

    float* out = (float*)d_out;                 // [B] f32
    float* s   = (float*)d_ws;                  // [B*S] f32 scratch (256 KB)

    const int rows = in_sizes[1];               // B*S = 65536
    const int B    = out_size;                  // 16

    // 4 waves/block * 8 rows/wave = 32 rows per block.
    score_kernel<<<rows / 32, 256, 0, stream>>>(x, mask, W, bias, s);
    window_max_kernel<<<B, 1024, 0, stream>>>(s, win, out);
}